// Round 5
// baseline (489.053 us; speedup 1.0000x reference)
//
#include <hip/hip_runtime.h>

#define IN_CH  256
#define HCC    256   // HEADS*OUT_CH
#define HEADS  4
#define OUTC   64
#define NEG_SLOPE 0.2f

// CSR binning parameters: bucket = 64 consecutive dst nodes
#define BW_SH   6
#define BW      64
#define MAXNB   2048          // supports N <= 131072
#define SRC_BITS 18
#define SRC_MASK 0x3FFFF

using short8v = __attribute__((ext_vector_type(8))) short;
using f32x4   = __attribute__((ext_vector_type(4))) float;

__device__ __forceinline__ unsigned short f2bf(float f) {
    unsigned u = __float_as_uint(f);
    unsigned r = (u + 0x7fffu + ((u >> 16) & 1u)) >> 16;  // RNE
    return (unsigned short)r;
}
__device__ __forceinline__ float bf2f(unsigned short b) {
    return __uint_as_float((unsigned)b << 16);
}

// ---------------------------------------------------------------------------
// Kernel 0: W [K=256][N=256] fp32 -> WT [N][K] bf16 (tiny, one-time)
// ---------------------------------------------------------------------------
__global__ void k_wt(const float* __restrict__ W,
                     unsigned short* __restrict__ WT) {
    int n = blockIdx.x;
    int k = threadIdx.x;
    WT[n * IN_CH + k] = f2bf(W[(size_t)k * HCC + n]);
}

// ---------------------------------------------------------------------------
// Kernel 1: x_lin = X @ W via bf16 MFMA, BM=64, BN=256 (X read once), BK=64.
// Wave w owns head w's 64 cols; attention logit dots fused in epilogue.
// ---------------------------------------------------------------------------
__global__ __launch_bounds__(256) void k_gemm(const float* __restrict__ X,
                                              const unsigned short* __restrict__ WT,
                                              const float* __restrict__ ASRC,
                                              const float* __restrict__ ADST,
                                              unsigned short* __restrict__ XLB,
                                              float* __restrict__ a_s,
                                              float* __restrict__ a_d,
                                              int N) {
    __shared__ unsigned short Ats[64][72];   // [m][k]
    __shared__ unsigned short Bs[256][72];   // [n][k]
    const int tid = threadIdx.x;
    const int lane = tid & 63;
    const int wid = tid >> 6;
    const int m0 = blockIdx.x * 64;
    const int r16 = lane & 15;
    const int g = lane >> 4;

    f32x4 acc[4][4];
    const f32x4 z = {0.f, 0.f, 0.f, 0.f};
#pragma unroll
    for (int m = 0; m < 4; ++m)
#pragma unroll
        for (int n = 0; n < 4; ++n) acc[m][n] = z;

    for (int kb = 0; kb < IN_CH; kb += 64) {
#pragma unroll
        for (int it = 0; it < 4; ++it) {
            int v = tid + 256 * it;
            int row = v >> 4;
            int c4 = (v & 15) << 2;
            int gr = m0 + row;
            float4 av = make_float4(0.f, 0.f, 0.f, 0.f);
            if (gr < N) av = *(const float4*)(X + (size_t)gr * IN_CH + kb + c4);
            ushort4 ab;
            ab.x = f2bf(av.x); ab.y = f2bf(av.y);
            ab.z = f2bf(av.z); ab.w = f2bf(av.w);
            *(ushort4*)&Ats[row][c4] = ab;
        }
#pragma unroll
        for (int it = 0; it < 8; ++it) {
            int v = tid + 256 * it;
            int brow = v >> 3;
            int c8 = (v & 7) << 3;
            short8v bv = *(const short8v*)(WT + (size_t)brow * IN_CH + kb + c8);
            *(short8v*)&Bs[brow][c8] = bv;
        }
        __syncthreads();
#pragma unroll
        for (int ks = 0; ks < 2; ++ks) {
            short8v af[4], bf[4];
#pragma unroll
            for (int m = 0; m < 4; ++m)
                af[m] = *(const short8v*)&Ats[m * 16 + r16][ks * 32 + g * 8];
#pragma unroll
            for (int n = 0; n < 4; ++n)
                bf[n] = *(const short8v*)&Bs[wid * 64 + n * 16 + r16][ks * 32 + g * 8];
#pragma unroll
            for (int m = 0; m < 4; ++m)
#pragma unroll
                for (int n = 0; n < 4; ++n)
                    acc[m][n] = __builtin_amdgcn_mfma_f32_16x16x32_bf16(
                        af[m], bf[n], acc[m][n], 0, 0, 0);
        }
        __syncthreads();
    }

    const int h = wid;
    float asc[4], adc[4];
#pragma unroll
    for (int n = 0; n < 4; ++n) {
        asc[n] = ASRC[h * OUTC + n * 16 + r16];
        adc[n] = ADST[h * OUTC + n * 16 + r16];
    }

    // epilogue: D frag layout col=lane&15, row=(lane>>4)*4+j  [m89-verified]
#pragma unroll
    for (int m = 0; m < 4; ++m) {
#pragma unroll
        for (int j = 0; j < 4; ++j) {
            int row = m0 + m * 16 + g * 4 + j;
            float ds = 0.f, dd = 0.f;
#pragma unroll
            for (int n = 0; n < 4; ++n) {
                ds = fmaf(acc[m][n][j], asc[n], ds);
                dd = fmaf(acc[m][n][j], adc[n], dd);
            }
#pragma unroll
            for (int o = 1; o < 16; o <<= 1) {
                ds += __shfl_xor(ds, o);
                dd += __shfl_xor(dd, o);
            }
            if (row < N) {
                if (r16 == 0) {
                    a_s[(size_t)row * HEADS + h] = ds;
                    a_d[(size_t)row * HEADS + h] = dd;
                }
#pragma unroll
                for (int n = 0; n < 4; ++n) {
                    int col = wid * 64 + n * 16 + r16;
                    XLB[(size_t)row * HCC + col] = f2bf(acc[m][n][j]);
                }
            }
        }
    }
}

// ---------------------------------------------------------------------------
// CSR build via 64-node-bucket counting sort (replaces random 4B scatter,
// which cost 108MB of write-allocate line traffic).
// ---------------------------------------------------------------------------

// Phase 1: bucket counts (per-block LDS histogram -> global atomics)
__global__ __launch_bounds__(256) void k_bcount(const int* __restrict__ ei,
                                                int* __restrict__ bcnt,
                                                int E, int nb) {
    __shared__ int h[MAXNB];
    int t = threadIdx.x;
    for (int j = t; j < nb; j += 256) h[j] = 0;
    __syncthreads();
    int base = blockIdx.x * 4096;
#pragma unroll
    for (int j = 0; j < 16; ++j) {
        int i = base + t + j * 256;
        if (i < E) atomicAdd(&h[ei[E + i] >> BW_SH], 1);
    }
    __syncthreads();
    for (int j = t; j < nb; j += 256) {
        int v = h[j];
        if (v) atomicAdd(&bcnt[j], v);
    }
}

// Phase 2: exclusive scan of bucket counts (single block, 512 thr x 4 each)
__global__ __launch_bounds__(512) void k_bscan(const int* __restrict__ bcnt,
                                               int* __restrict__ bbase,
                                               int* __restrict__ bfill,
                                               int E, int nb) {
    __shared__ int s[512];
    int t = threadIdx.x;
    int c[4];
    int sum = 0;
#pragma unroll
    for (int i = 0; i < 4; ++i) {
        int j = t * 4 + i;
        c[i] = (j < nb) ? bcnt[j] : 0;
        sum += c[i];
    }
    s[t] = sum;
    __syncthreads();
    for (int off = 1; off < 512; off <<= 1) {
        int x = (t >= off) ? s[t - off] : 0;
        __syncthreads();
        s[t] += x;
        __syncthreads();
    }
    int run = s[t] - sum;  // exclusive
#pragma unroll
    for (int i = 0; i < 4; ++i) {
        int j = t * 4 + i;
        if (j < nb) {
            bbase[j] = run;
            bfill[j] = run;
            run += c[i];
        }
    }
    if (t == 0) bbase[nb] = E;
}

// Phase 3: scatter packed edges into bucket segments (sequential slots per
// bucket -> full line utilization)
__global__ __launch_bounds__(256) void k_bscatter(const int* __restrict__ ei,
                                                  int* __restrict__ bfill,
                                                  unsigned* __restrict__ bucketed,
                                                  int E) {
    int base = blockIdx.x * 2048;
#pragma unroll
    for (int j = 0; j < 8; ++j) {
        int i = base + threadIdx.x + j * 256;
        if (i < E) {
            int src = ei[i];
            int dst = ei[E + i];
            int pos = atomicAdd(&bfill[dst >> BW_SH], 1);
            bucketed[pos] = ((unsigned)(dst & (BW - 1)) << SRC_BITS) |
                            (unsigned)src;
        }
    }
}

// Phase 4: per-bucket CSR finalize: 64-counter histogram + wave scan,
// scatter eid within the bucket's (L2-resident) output region; inject
// self-loops. Bucket b's output base = bbase[b] + 64*b.
__global__ __launch_bounds__(256) void k_bbuild(const int* __restrict__ bbase,
                                                const unsigned* __restrict__ bucketed,
                                                int* __restrict__ rowptr,
                                                int* __restrict__ eid,
                                                int N, int nb) {
    __shared__ int cnt64[BW];
    __shared__ int fill64[BW];
    int b = blockIdx.x;
    int t = threadIdx.x;
    int s0 = bbase[b];
    int s1 = bbase[b + 1];
    int cnt = s1 - s0;
    int nloc = N - b * BW;
    if (nloc > BW) nloc = BW;
    if (t < BW) cnt64[t] = 0;
    __syncthreads();
    for (int i = t; i < cnt; i += 256)
        atomicAdd(&cnt64[(bucketed[s0 + i] >> SRC_BITS) & (BW - 1)], 1);
    __syncthreads();
    if (t < BW) {
        int own = cnt64[t] + (t < nloc ? 1 : 0);  // +1 self-loop
        int val = own;
#pragma unroll
        for (int off = 1; off < BW; off <<= 1) {
            int v2 = __shfl_up(val, off);
            if (t >= off) val += v2;
        }
        int excl = val - own;
        int out0 = s0 + b * BW + excl;
        if (t < nloc) rowptr[b * BW + t] = out0;
        fill64[t] = out0;
    }
    if (b == nb - 1 && t == 0) rowptr[N] = s1 + b * BW + nloc;
    __syncthreads();
    // self-loops first
    if (t < nloc) {
        int node = b * BW + t;
        int pos = atomicAdd(&fill64[t], 1);
        eid[pos] = node;
    }
    for (int i = t; i < cnt; i += 256) {
        unsigned u = bucketed[s0 + i];
        int dl = (u >> SRC_BITS) & (BW - 1);
        int pos = atomicAdd(&fill64[dl], 1);
        eid[pos] = (int)(u & SRC_MASK);
    }
}

// ---------------------------------------------------------------------------
// Kernel 3: per-dst softmax + aggregation. One WAVE per node, lane owns 4
// channels. Unrolled by 8 edges for gather MLP. No max subtraction (logits
// O(8), fp32 exp safe).
// ---------------------------------------------------------------------------
__global__ __launch_bounds__(256) void k_agg(const int* __restrict__ rowptr,
                                             const int* __restrict__ eid,
                                             const float* __restrict__ a_s,
                                             const float* __restrict__ a_d,
                                             const unsigned short* __restrict__ XLB,
                                             const float* __restrict__ BIAS,
                                             float* __restrict__ OUT, int N) {
    int wid = threadIdx.x >> 6;
    int lane = threadIdx.x & 63;
    int n = blockIdx.x * 4 + wid;
    if (n >= N) return;
    int h = lane >> 4;
    int s0 = rowptr[n];
    int s1 = rowptr[n + 1];
    float adn = a_d[(size_t)n * HEADS + h];
    float s = 0.f;
    float acc0 = 0.f, acc1 = 0.f, acc2 = 0.f, acc3 = 0.f;

    int e = s0;
    for (; e + 8 <= s1; e += 8) {
        int idx[8];
#pragma unroll
        for (int j = 0; j < 8; ++j) idx[j] = eid[e + j];
        float l[8];
#pragma unroll
        for (int j = 0; j < 8; ++j) l[j] = a_s[(size_t)idx[j] * HEADS + h] + adn;
        ushort4 xv[8];
#pragma unroll
        for (int j = 0; j < 8; ++j)
            xv[j] = *(const ushort4*)(XLB + (size_t)idx[j] * HCC + lane * 4);
#pragma unroll
        for (int j = 0; j < 8; ++j) {
            float lj = fmaxf(l[j], NEG_SLOPE * l[j]);
            float p = __expf(lj);
            s += p;
            acc0 = fmaf(p, bf2f(xv[j].x), acc0);
            acc1 = fmaf(p, bf2f(xv[j].y), acc1);
            acc2 = fmaf(p, bf2f(xv[j].z), acc2);
            acc3 = fmaf(p, bf2f(xv[j].w), acc3);
        }
    }
    for (; e + 4 <= s1; e += 4) {
        int idx[4];
#pragma unroll
        for (int j = 0; j < 4; ++j) idx[j] = eid[e + j];
        float l[4];
#pragma unroll
        for (int j = 0; j < 4; ++j) l[j] = a_s[(size_t)idx[j] * HEADS + h] + adn;
        ushort4 xv[4];
#pragma unroll
        for (int j = 0; j < 4; ++j)
            xv[j] = *(const ushort4*)(XLB + (size_t)idx[j] * HCC + lane * 4);
#pragma unroll
        for (int j = 0; j < 4; ++j) {
            float lj = fmaxf(l[j], NEG_SLOPE * l[j]);
            float p = __expf(lj);
            s += p;
            acc0 = fmaf(p, bf2f(xv[j].x), acc0);
            acc1 = fmaf(p, bf2f(xv[j].y), acc1);
            acc2 = fmaf(p, bf2f(xv[j].z), acc2);
            acc3 = fmaf(p, bf2f(xv[j].w), acc3);
        }
    }
    for (; e < s1; ++e) {
        int src = eid[e];
        float l = a_s[(size_t)src * HEADS + h] + adn;
        l = fmaxf(l, NEG_SLOPE * l);
        float p = __expf(l);
        ushort4 xv = *(const ushort4*)(XLB + (size_t)src * HCC + lane * 4);
        s += p;
        acc0 = fmaf(p, bf2f(xv.x), acc0);
        acc1 = fmaf(p, bf2f(xv.y), acc1);
        acc2 = fmaf(p, bf2f(xv.z), acc2);
        acc3 = fmaf(p, bf2f(xv.w), acc3);
    }

    float inv = 1.f / (s + 1e-16f);
    float4 b = *(const float4*)(BIAS + lane * 4);
    float4 o;
    o.x = acc0 * inv + b.x;
    o.y = acc1 * inv + b.y;
    o.z = acc2 * inv + b.z;
    o.w = acc3 * inv + b.w;
    *(float4*)(OUT + (size_t)n * HCC + lane * 4) = o;
}

// ---------------------------------------------------------------------------
extern "C" void kernel_launch(void* const* d_in, const int* in_sizes, int n_in,
                              void* d_out, int out_size, void* d_ws,
                              size_t ws_size, hipStream_t stream) {
    const float* X = (const float*)d_in[0];
    const int* EI = (const int*)d_in[1];
    const float* W = (const float*)d_in[2];
    const float* ASRC = (const float*)d_in[3];
    const float* ADST = (const float*)d_in[4];
    const float* BIAS = (const float*)d_in[5];
    float* OUT = (float*)d_out;

    const int N = in_sizes[0] / IN_CH;
    const int E = in_sizes[1] / 2;
    const int ET = E + N;
    const int nb = (N + BW - 1) >> BW_SH;

    // workspace layout (all 256B aligned)
    char* w = (char*)d_ws;
    auto align = [](size_t x) { return (x + 255) & ~(size_t)255; };
    size_t o = 0;
    unsigned short* xlb = (unsigned short*)(w + o); o += align((size_t)N * HCC * 2);
    unsigned short* wt = (unsigned short*)(w + o);  o += align((size_t)IN_CH * HCC * 2);
    float* a_s = (float*)(w + o); o += align((size_t)N * HEADS * 4);
    float* a_d = (float*)(w + o); o += align((size_t)N * HEADS * 4);
    int* rowptr = (int*)(w + o);  o += align((size_t)(N + 1) * 4);
    int* eid = (int*)(w + o);     o += align((size_t)ET * 4);
    unsigned* bucketed = (unsigned*)(w + o); o += align((size_t)E * 4);
    int* bcnt = (int*)(w + o);    o += align((size_t)(nb + 1) * 4);
    int* bbase = (int*)(w + o);   o += align((size_t)(nb + 1) * 4);
    int* bfill = (int*)(w + o);   o += align((size_t)nb * 4);

    // 0. W -> WT (bf16, transposed)
    k_wt<<<HCC, IN_CH, 0, stream>>>(W, wt);

    // 1. linear projection -> bf16 x_lin + fused attention logits (MFMA)
    k_gemm<<<(N + 63) / 64, 256, 0, stream>>>(X, wt, ASRC, ADST, xlb, a_s,
                                              a_d, N);

    // 2. CSR build via bucket counting sort
    hipMemsetAsync(bcnt, 0, (size_t)nb * 4, stream);
    k_bcount<<<(E + 4095) / 4096, 256, 0, stream>>>(EI, bcnt, E, nb);
    k_bscan<<<1, 512, 0, stream>>>(bcnt, bbase, bfill, E, nb);
    k_bscatter<<<(E + 2047) / 2048, 256, 0, stream>>>(EI, bfill, bucketed, E);
    k_bbuild<<<nb, 256, 0, stream>>>(bbase, bucketed, rowptr, eid, N, nb);

    // 3. per-dst softmax + weighted aggregation (one wave per node)
    k_agg<<<(N + 3) / 4, 256, 0, stream>>>(rowptr, eid, a_s, a_d, xlb, BIAS,
                                           OUT, N);
}

// Round 6
// 365.891 us; speedup vs baseline: 1.3366x; 1.3366x over previous
//
#include <hip/hip_runtime.h>

#define IN_CH  256
#define HCC    256   // HEADS*OUT_CH
#define HEADS  4
#define OUTC   64
#define NEG_SLOPE 0.2f
#define NSHARD 8     // XCD count; blockIdx%8 ~ XCD (round-robin dispatch)
#define SUBG   120   // blocks per shard

using short8v = __attribute__((ext_vector_type(8))) short;
using f32x4   = __attribute__((ext_vector_type(4))) float;

__device__ __forceinline__ unsigned short f2bf(float f) {
    unsigned u = __float_as_uint(f);
    unsigned r = (u + 0x7fffu + ((u >> 16) & 1u)) >> 16;  // RNE
    return (unsigned short)r;
}
__device__ __forceinline__ float bf2f(unsigned short b) {
    return __uint_as_float((unsigned)b << 16);
}

// ---------------------------------------------------------------------------
// Kernel 0: W [K=256][N=256] fp32 -> WT [N][K] bf16 (tiny, one-time)
// ---------------------------------------------------------------------------
__global__ void k_wt(const float* __restrict__ W,
                     unsigned short* __restrict__ WT) {
    int n = blockIdx.x;
    int k = threadIdx.x;
    WT[n * IN_CH + k] = f2bf(W[(size_t)k * HCC + n]);
}

// ---------------------------------------------------------------------------
// Kernel 1: x_lin = X @ W via bf16 MFMA, BM=64, BN=256 (X read once), BK=64.
// Wave w owns head w's 64 cols; attention logit dots fused in epilogue.
// ---------------------------------------------------------------------------
__global__ __launch_bounds__(256) void k_gemm(const float* __restrict__ X,
                                              const unsigned short* __restrict__ WT,
                                              const float* __restrict__ ASRC,
                                              const float* __restrict__ ADST,
                                              unsigned short* __restrict__ XLB,
                                              float* __restrict__ a_s,
                                              float* __restrict__ a_d,
                                              int N) {
    __shared__ unsigned short Ats[64][72];   // [m][k]
    __shared__ unsigned short Bs[256][72];   // [n][k]
    const int tid = threadIdx.x;
    const int lane = tid & 63;
    const int wid = tid >> 6;
    const int m0 = blockIdx.x * 64;
    const int r16 = lane & 15;
    const int g = lane >> 4;

    f32x4 acc[4][4];
    const f32x4 z = {0.f, 0.f, 0.f, 0.f};
#pragma unroll
    for (int m = 0; m < 4; ++m)
#pragma unroll
        for (int n = 0; n < 4; ++n) acc[m][n] = z;

    for (int kb = 0; kb < IN_CH; kb += 64) {
#pragma unroll
        for (int it = 0; it < 4; ++it) {
            int v = tid + 256 * it;
            int row = v >> 4;
            int c4 = (v & 15) << 2;
            int gr = m0 + row;
            float4 av = make_float4(0.f, 0.f, 0.f, 0.f);
            if (gr < N) av = *(const float4*)(X + (size_t)gr * IN_CH + kb + c4);
            ushort4 ab;
            ab.x = f2bf(av.x); ab.y = f2bf(av.y);
            ab.z = f2bf(av.z); ab.w = f2bf(av.w);
            *(ushort4*)&Ats[row][c4] = ab;
        }
#pragma unroll
        for (int it = 0; it < 8; ++it) {
            int v = tid + 256 * it;
            int brow = v >> 3;
            int c8 = (v & 7) << 3;
            short8v bv = *(const short8v*)(WT + (size_t)brow * IN_CH + kb + c8);
            *(short8v*)&Bs[brow][c8] = bv;
        }
        __syncthreads();
#pragma unroll
        for (int ks = 0; ks < 2; ++ks) {
            short8v af[4], bf[4];
#pragma unroll
            for (int m = 0; m < 4; ++m)
                af[m] = *(const short8v*)&Ats[m * 16 + r16][ks * 32 + g * 8];
#pragma unroll
            for (int n = 0; n < 4; ++n)
                bf[n] = *(const short8v*)&Bs[wid * 64 + n * 16 + r16][ks * 32 + g * 8];
#pragma unroll
            for (int m = 0; m < 4; ++m)
#pragma unroll
                for (int n = 0; n < 4; ++n)
                    acc[m][n] = __builtin_amdgcn_mfma_f32_16x16x32_bf16(
                        af[m], bf[n], acc[m][n], 0, 0, 0);
        }
        __syncthreads();
    }

    const int h = wid;
    float asc[4], adc[4];
#pragma unroll
    for (int n = 0; n < 4; ++n) {
        asc[n] = ASRC[h * OUTC + n * 16 + r16];
        adc[n] = ADST[h * OUTC + n * 16 + r16];
    }

    // epilogue: D frag layout col=lane&15, row=(lane>>4)*4+j  [m89-verified]
#pragma unroll
    for (int m = 0; m < 4; ++m) {
#pragma unroll
        for (int j = 0; j < 4; ++j) {
            int row = m0 + m * 16 + g * 4 + j;
            float ds = 0.f, dd = 0.f;
#pragma unroll
            for (int n = 0; n < 4; ++n) {
                ds = fmaf(acc[m][n][j], asc[n], ds);
                dd = fmaf(acc[m][n][j], adc[n], dd);
            }
#pragma unroll
            for (int o = 1; o < 16; o <<= 1) {
                ds += __shfl_xor(ds, o);
                dd += __shfl_xor(dd, o);
            }
            if (row < N) {
                if (r16 == 0) {
                    a_s[(size_t)row * HEADS + h] = ds;
                    a_d[(size_t)row * HEADS + h] = dd;
                }
#pragma unroll
                for (int n = 0; n < 4; ++n) {
                    int col = wid * 64 + n * 16 + r16;
                    XLB[(size_t)row * HCC + col] = f2bf(acc[m][n][j]);
                }
            }
        }
    }
}

// ---------------------------------------------------------------------------
// CSR build, XCD-sharded: shard s = blockIdx%8 only commits edges whose dst
// lies in node range [s*N/8,(s+1)*N/8). deg/fill counters and eid region for
// a shard are then only touched by one XCD -> lines accumulate in that L2
// and write back full (kills the 108MB write-allocate thrash of a global
// random 4B scatter). Reads sweep ei 8x but are L3-served.
// ---------------------------------------------------------------------------
__global__ __launch_bounds__(256) void k_deg(const int* __restrict__ ei,
                                             int* __restrict__ deg,
                                             int E, int N) {
    int shard = blockIdx.x & (NSHARD - 1);
    int sub = blockIdx.x >> 3;
    int lo = (int)((long long)shard * N / NSHARD);
    int hi = (int)((long long)(shard + 1) * N / NSHARD);
    int ET = E + N;
    for (int i = sub * 256 + threadIdx.x; i < ET; i += SUBG * 256) {
        int dst = (i < E) ? ei[E + i] : (i - E);
        if (dst >= lo && dst < hi) atomicAdd(&deg[dst], 1);
    }
}

__global__ void k_scan1(const int* __restrict__ in, int* __restrict__ part,
                        int* __restrict__ bsum, int N) {
    __shared__ int s[256];
    int t = threadIdx.x;
    int i = blockIdx.x * 256 + t;
    int v = (i < N) ? in[i] : 0;
    s[t] = v;
    __syncthreads();
    for (int off = 1; off < 256; off <<= 1) {
        int x = (t >= off) ? s[t - off] : 0;
        __syncthreads();
        s[t] += x;
        __syncthreads();
    }
    if (i < N) part[i] = s[t];
    if (t == 255) bsum[blockIdx.x] = s[255];
}

__global__ void k_scan2(const int* __restrict__ bsum, int* __restrict__ binc,
                        int nb) {
    __shared__ int s[512];
    int t = threadIdx.x;
    s[t] = (t < nb) ? bsum[t] : 0;
    __syncthreads();
    for (int off = 1; off < 512; off <<= 1) {
        int x = (t >= off) ? s[t - off] : 0;
        __syncthreads();
        s[t] += x;
        __syncthreads();
    }
    binc[t] = s[t];
}

__global__ void k_scan3(const int* __restrict__ part,
                        const int* __restrict__ binc,
                        int* __restrict__ rowptr, int N) {
    int b = blockIdx.x;
    int i = b * 256 + threadIdx.x;
    if (i >= N) return;
    int off = (b > 0) ? binc[b - 1] : 0;
    rowptr[i + 1] = part[i] + off;
    if (i == 0) rowptr[0] = 0;
}

__global__ __launch_bounds__(256) void k_scatter(const int* __restrict__ ei,
                                                 int* __restrict__ fill,
                                                 int* __restrict__ eid,
                                                 int E, int N) {
    int shard = blockIdx.x & (NSHARD - 1);
    int sub = blockIdx.x >> 3;
    int lo = (int)((long long)shard * N / NSHARD);
    int hi = (int)((long long)(shard + 1) * N / NSHARD);
    int ET = E + N;
    for (int i = sub * 256 + threadIdx.x; i < ET; i += SUBG * 256) {
        int src, dst;
        if (i < E) {
            src = ei[i];
            dst = ei[E + i];
        } else {
            src = dst = i - E;
        }
        if (dst >= lo && dst < hi) {
            int pos = atomicAdd(&fill[dst], 1);
            eid[pos] = src;
        }
    }
}

// ---------------------------------------------------------------------------
// Kernel 3: per-dst softmax + aggregation. One WAVE per node, lane owns 4
// channels. Unrolled by 8 edges for gather MLP. No max subtraction (logits
// O(8), fp32 exp safe).
// ---------------------------------------------------------------------------
__global__ __launch_bounds__(256) void k_agg(const int* __restrict__ rowptr,
                                             const int* __restrict__ eid,
                                             const float* __restrict__ a_s,
                                             const float* __restrict__ a_d,
                                             const unsigned short* __restrict__ XLB,
                                             const float* __restrict__ BIAS,
                                             float* __restrict__ OUT, int N) {
    int wid = threadIdx.x >> 6;
    int lane = threadIdx.x & 63;
    int n = blockIdx.x * 4 + wid;
    if (n >= N) return;
    int h = lane >> 4;
    int s0 = rowptr[n];
    int s1 = rowptr[n + 1];
    float adn = a_d[(size_t)n * HEADS + h];
    float s = 0.f;
    float acc0 = 0.f, acc1 = 0.f, acc2 = 0.f, acc3 = 0.f;

    int e = s0;
    for (; e + 8 <= s1; e += 8) {
        int idx[8];
#pragma unroll
        for (int j = 0; j < 8; ++j) idx[j] = eid[e + j];
        float l[8];
#pragma unroll
        for (int j = 0; j < 8; ++j) l[j] = a_s[(size_t)idx[j] * HEADS + h] + adn;
        ushort4 xv[8];
#pragma unroll
        for (int j = 0; j < 8; ++j)
            xv[j] = *(const ushort4*)(XLB + (size_t)idx[j] * HCC + lane * 4);
#pragma unroll
        for (int j = 0; j < 8; ++j) {
            float lj = fmaxf(l[j], NEG_SLOPE * l[j]);
            float p = __expf(lj);
            s += p;
            acc0 = fmaf(p, bf2f(xv[j].x), acc0);
            acc1 = fmaf(p, bf2f(xv[j].y), acc1);
            acc2 = fmaf(p, bf2f(xv[j].z), acc2);
            acc3 = fmaf(p, bf2f(xv[j].w), acc3);
        }
    }
    for (; e + 4 <= s1; e += 4) {
        int idx[4];
#pragma unroll
        for (int j = 0; j < 4; ++j) idx[j] = eid[e + j];
        float l[4];
#pragma unroll
        for (int j = 0; j < 4; ++j) l[j] = a_s[(size_t)idx[j] * HEADS + h] + adn;
        ushort4 xv[4];
#pragma unroll
        for (int j = 0; j < 4; ++j)
            xv[j] = *(const ushort4*)(XLB + (size_t)idx[j] * HCC + lane * 4);
#pragma unroll
        for (int j = 0; j < 4; ++j) {
            float lj = fmaxf(l[j], NEG_SLOPE * l[j]);
            float p = __expf(lj);
            s += p;
            acc0 = fmaf(p, bf2f(xv[j].x), acc0);
            acc1 = fmaf(p, bf2f(xv[j].y), acc1);
            acc2 = fmaf(p, bf2f(xv[j].z), acc2);
            acc3 = fmaf(p, bf2f(xv[j].w), acc3);
        }
    }
    for (; e < s1; ++e) {
        int src = eid[e];
        float l = a_s[(size_t)src * HEADS + h] + adn;
        l = fmaxf(l, NEG_SLOPE * l);
        float p = __expf(l);
        ushort4 xv = *(const ushort4*)(XLB + (size_t)src * HCC + lane * 4);
        s += p;
        acc0 = fmaf(p, bf2f(xv.x), acc0);
        acc1 = fmaf(p, bf2f(xv.y), acc1);
        acc2 = fmaf(p, bf2f(xv.z), acc2);
        acc3 = fmaf(p, bf2f(xv.w), acc3);
    }

    float inv = 1.f / (s + 1e-16f);
    float4 b = *(const float4*)(BIAS + lane * 4);
    float4 o;
    o.x = acc0 * inv + b.x;
    o.y = acc1 * inv + b.y;
    o.z = acc2 * inv + b.z;
    o.w = acc3 * inv + b.w;
    *(float4*)(OUT + (size_t)n * HCC + lane * 4) = o;
}

// ---------------------------------------------------------------------------
extern "C" void kernel_launch(void* const* d_in, const int* in_sizes, int n_in,
                              void* d_out, int out_size, void* d_ws,
                              size_t ws_size, hipStream_t stream) {
    const float* X = (const float*)d_in[0];
    const int* EI = (const int*)d_in[1];
    const float* W = (const float*)d_in[2];
    const float* ASRC = (const float*)d_in[3];
    const float* ADST = (const float*)d_in[4];
    const float* BIAS = (const float*)d_in[5];
    float* OUT = (float*)d_out;

    const int N = in_sizes[0] / IN_CH;
    const int E = in_sizes[1] / 2;
    const int ET = E + N;

    // workspace layout (all 256B aligned)
    char* w = (char*)d_ws;
    auto align = [](size_t x) { return (x + 255) & ~(size_t)255; };
    size_t o = 0;
    unsigned short* xlb = (unsigned short*)(w + o); o += align((size_t)N * HCC * 2);
    unsigned short* wt = (unsigned short*)(w + o);  o += align((size_t)IN_CH * HCC * 2);
    float* a_s = (float*)(w + o); o += align((size_t)N * HEADS * 4);
    float* a_d = (float*)(w + o); o += align((size_t)N * HEADS * 4);
    int* deg = (int*)(w + o);     o += align((size_t)N * 4);
    int* rowptr = (int*)(w + o);  o += align((size_t)(N + 1) * 4);
    int* fill = (int*)(w + o);    o += align((size_t)N * 4);
    int* eid = (int*)(w + o);     o += align((size_t)ET * 4);
    int* part = (int*)(w + o);    o += align((size_t)N * 4);
    int* bsum = (int*)(w + o);    o += align(512 * 4);
    int* binc = (int*)(w + o);    o += align(512 * 4);

    // 0. W -> WT (bf16, transposed)
    k_wt<<<HCC, IN_CH, 0, stream>>>(W, wt);

    // 1. linear projection -> bf16 x_lin + fused attention logits (MFMA)
    k_gemm<<<(N + 63) / 64, 256, 0, stream>>>(X, wt, ASRC, ADST, xlb, a_s,
                                              a_d, N);

    // 2. CSR build (XCD-sharded histogram + scan + XCD-sharded scatter)
    hipMemsetAsync(deg, 0, (size_t)N * 4, stream);
    k_deg<<<NSHARD * SUBG, 256, 0, stream>>>(EI, deg, E, N);
    int nb1 = (N + 255) / 256;
    k_scan1<<<nb1, 256, 0, stream>>>(deg, part, bsum, N);
    k_scan2<<<1, 512, 0, stream>>>(bsum, binc, nb1);
    k_scan3<<<nb1, 256, 0, stream>>>(part, binc, rowptr, N);
    hipMemcpyAsync(fill, rowptr, (size_t)N * 4, hipMemcpyDeviceToDevice,
                   stream);
    k_scatter<<<NSHARD * SUBG, 256, 0, stream>>>(EI, fill, eid, E, N);

    // 3. per-dst softmax + weighted aggregation (one wave per node)
    k_agg<<<(N + 3) / 4, 256, 0, stream>>>(rowptr, eid, a_s, a_d, xlb, BIAS,
                                           OUT, N);
}